// Round 1
// baseline (84.831 us; speedup 1.0000x reference)
//
#include <hip/hip_runtime.h>
#include <math.h>

#define N_IN   128
#define N_OUT  128
#define KDEG   3
#define GQ     8
#define NB     (GQ + KDEG)        // 11 basis funcs
#define NK     (GQ + 2*KDEG + 1)  // 15 knots
#define BATCH  512
#define B_TILE 8
#define O_TILE 16
#define FJ     12                 // 11 basis + 1 silu slot
#define FSTRIDE (N_IN * FJ + 4)   // 1540: pad so b-stride % 32 == 4 (bank spread)

__global__ __launch_bounds__(256) void kan_fused(
    const float* __restrict__ x, const float* __restrict__ grid,
    const float* __restrict__ c_basis, const float* __restrict__ c_res,
    const float* __restrict__ c_spl, float* __restrict__ out)
{
    __shared__ float f[B_TILE * FSTRIDE];   // ~49.3 KB
    __shared__ float part[256];
    const int t  = threadIdx.x;
    const int b0 = blockIdx.x * B_TILE;
    const int o0 = blockIdx.y * O_TILE;

    // ---- Phase 1: B-spline basis + silu for the 8x128 (b,i) tile -> LDS ----
    for (int p = t; p < B_TILE * N_IN; p += 256) {
        const int bl = p >> 7;     // local batch row 0..7
        const int i  = p & 127;    // input feature
        const float xv = x[(b0 + bl) * N_IN + i];

        float tk[NK];
        #pragma unroll
        for (int m = 0; m < NK; ++m) tk[m] = grid[i * NK + m];

        float bb[NK - 1];
        #pragma unroll
        for (int m = 0; m < NK - 1; ++m)
            bb[m] = (xv >= tk[m] && xv < tk[m + 1]) ? 1.0f : 0.0f;

        #pragma unroll
        for (int kd = 1; kd <= KDEG; ++kd) {
            #pragma unroll
            for (int m = 0; m + kd < NK - 1; ++m) {
                const float l = (xv - tk[m]) / (tk[m + kd] - tk[m]);
                const float r = (tk[m + kd + 1] - xv) / (tk[m + kd + 1] - tk[m + 1]);
                bb[m] = l * bb[m] + r * bb[m + 1];
            }
        }

        float* fp = &f[bl * FSTRIDE + i * FJ];
        #pragma unroll
        for (int j = 0; j < NB; ++j) fp[j] = bb[j];
        fp[NB] = xv / (1.0f + __expf(-xv));     // silu(x)
    }
    __syncthreads();

    // ---- Phase 2: 128 outputs (8b x 16o), 2 threads/output split the i-range ----
    const int half = t >> 7;          // 0 or 1
    const int tt   = t & 127;
    const int ol   = tt & 15;
    const int bl   = tt >> 4;         // 0..7
    const int og   = o0 + ol;
    const float* fb = &f[bl * FSTRIDE];

    float acc = 0.0f;
    const int i_beg = half * (N_IN / 2);
    const int i_end = i_beg + (N_IN / 2);
    for (int i = i_beg; i < i_end; ++i) {
        const float* fp = &fb[i * FJ];
        const float* cb = &c_basis[(og * N_IN + i) * NB];
        float s = 0.0f;
        #pragma unroll
        for (int j = 0; j < NB; ++j) s += cb[j] * fp[j];
        acc += fp[NB] * c_res[og * N_IN + i] + c_spl[og * N_IN + i] * s;
    }
    part[t] = acc;
    __syncthreads();

    if (t < 128) {
        out[(b0 + bl) * N_OUT + og] = part[t] + part[t + 128];
    }
}

extern "C" void kernel_launch(void* const* d_in, const int* in_sizes, int n_in,
                              void* d_out, int out_size, void* d_ws, size_t ws_size,
                              hipStream_t stream) {
    const float* x       = (const float*)d_in[0];
    const float* grid    = (const float*)d_in[1];
    const float* c_basis = (const float*)d_in[2];
    const float* c_res   = (const float*)d_in[3];
    const float* c_spl   = (const float*)d_in[4];
    float* out = (float*)d_out;

    dim3 g(BATCH / B_TILE, N_OUT / O_TILE);   // 64 x 8 = 512 blocks
    kan_fused<<<g, 256, 0, stream>>>(x, grid, c_basis, c_res, c_spl, out);
}

// Round 2
// 54.156 us; speedup vs baseline: 1.5664x; 1.5664x over previous
//
#include <hip/hip_runtime.h>
#include <math.h>

#define N_IN   128
#define N_OUT  128
#define NB     11                 // basis funcs per edge
#define FJ     12                 // 11 basis + 1 (silu/res) slot
#define BATCH  512
#define B_TILE 4
#define O_TILE 16
#define FSTR   (N_IN * FJ + 4)    // 1540 floats: +4 pad spreads banks across b rows
#define FSTR_FB (N_IN * 8 + 4)    // fallback record stride

// ---- Kernel 1: packed weights pw[e][j] = c_spl[e]*c_basis[e][j], pw[e][11]=c_res[e]
// Row = 48 B, 16B-aligned -> main kernel reads 3x dwordx4 per (o,i).
__global__ __launch_bounds__(256) void pw_build(
    const float* __restrict__ c_basis, const float* __restrict__ c_res,
    const float* __restrict__ c_spl, float* __restrict__ pw)
{
    const int e = blockIdx.x * 256 + threadIdx.x;   // 0 .. 16383 (= o*128+i)
    const float s = c_spl[e];
    const float* src = c_basis + e * NB;
    float4 a, b, c;
    a.x = s * src[0];  a.y = s * src[1];  a.z = s * src[2];  a.w = s * src[3];
    b.x = s * src[4];  b.y = s * src[5];  b.z = s * src[6];  b.w = s * src[7];
    c.x = s * src[8];  c.y = s * src[9];  c.z = s * src[10]; c.w = c_res[e];
    float4* dst = (float4*)(pw + (size_t)e * FJ);
    dst[0] = a; dst[1] = b; dst[2] = c;
}

// ---- Main kernel. PW=1: dense-12 dot vs packed weights. PW=0: direct gather fallback.
template <int PW>
__global__ __launch_bounds__(256) void kan_main(
    const float* __restrict__ x, const float* __restrict__ grid,
    const float* __restrict__ c_basis, const float* __restrict__ c_res,
    const float* __restrict__ c_spl, const float* __restrict__ pw,
    float* __restrict__ out)
{
    __shared__ float f[B_TILE * (PW ? FSTR : FSTR_FB)];
    __shared__ float part[256];
    const int t  = threadIdx.x;
    const int b0 = blockIdx.x * B_TILE;
    const int o0 = blockIdx.y * O_TILE;

    // ---- Phase 1: closed-form uniform cubic B-spline + silu -> LDS ----
    const float lo = grid[3];                  // knot[3] = grid lo
    const float hr = 1.0f / (grid[4] - grid[3]);
    for (int p = t; p < B_TILE * N_IN; p += 256) {
        const int bl = p >> 7;
        const int i  = p & 127;
        const float xv = x[(b0 + bl) * N_IN + i];
        const float s  = (xv - lo) * hr;       // in [0,8)
        int c = (int)s; c = c < 0 ? 0 : (c > 7 ? 7 : c);
        const float u  = s - (float)c;
        const float um = 1.0f - u;
        const float u2 = u * u, u3 = u2 * u;
        const float B0 = um * um * um * (1.0f / 6.0f);
        const float B1 = (3.0f * u3 - 6.0f * u2 + 4.0f) * (1.0f / 6.0f);
        const float B2 = (-3.0f * u3 + 3.0f * u2 + 3.0f * u + 1.0f) * (1.0f / 6.0f);
        const float B3 = u3 * (1.0f / 6.0f);
        const float si = xv / (1.0f + __expf(-xv));
        if (PW) {
            float* fp = &f[bl * FSTR + i * FJ];
            float4 z = {0.f, 0.f, 0.f, 0.f};
            ((float4*)fp)[0] = z; ((float4*)fp)[1] = z; ((float4*)fp)[2] = z;
            fp[c] = B0; fp[c + 1] = B1; fp[c + 2] = B2; fp[c + 3] = B3;  // LDS runtime idx ok
            fp[11] = si;
        } else {
            float* fp = &f[bl * FSTR_FB + i * 8];
            float4 w = {B0, B1, B2, B3};
            ((float4*)fp)[0] = w;
            fp[4] = si; fp[5] = (float)c;
        }
    }
    __syncthreads();

    // ---- Phase 2: 64 outputs (4b x 16o), 4 threads/output split the i-range ----
    const int q  = t >> 6;            // i-quarter 0..3 (one wave per quarter)
    const int tt = t & 63;
    const int ol = tt & 15;
    const int bl = tt >> 4;
    const int og = o0 + ol;
    float acc = 0.0f;

    if (PW) {
        const float* fb = &f[bl * FSTR];
        const float4* wbase = (const float4*)(pw + (size_t)(og * N_IN) * FJ);
        #pragma unroll 4
        for (int i = q * 32; i < q * 32 + 32; ++i) {
            const float4* fp = (const float4*)&fb[i * FJ];
            const float4 f0 = fp[0], f1 = fp[1], f2 = fp[2];
            const float4 w0 = wbase[i * 3], w1 = wbase[i * 3 + 1], w2 = wbase[i * 3 + 2];
            acc += f0.x * w0.x + f0.y * w0.y + f0.z * w0.z + f0.w * w0.w
                 + f1.x * w1.x + f1.y * w1.y + f1.z * w1.z + f1.w * w1.w
                 + f2.x * w2.x + f2.y * w2.y + f2.z * w2.z + f2.w * w2.w;
        }
    } else {
        const float* fb = &f[bl * FSTR_FB];
        #pragma unroll 2
        for (int i = q * 32; i < q * 32 + 32; ++i) {
            const float4 w = ((const float4*)&fb[i * 8])[0];
            const float si = fb[i * 8 + 4];
            const int   c  = (int)fb[i * 8 + 5];
            const int   e  = og * N_IN + i;
            const float* cbp = &c_basis[e * NB + c];
            const float sum = w.x * cbp[0] + w.y * cbp[1] + w.z * cbp[2] + w.w * cbp[3];
            acc += si * c_res[e] + c_spl[e] * sum;
        }
    }
    part[t] = acc;
    __syncthreads();

    if (t < 64) {
        const int obl = t >> 4, ool = t & 15;
        out[(b0 + obl) * N_OUT + (o0 + ool)] =
            part[t] + part[t + 64] + part[t + 128] + part[t + 192];
    }
}

extern "C" void kernel_launch(void* const* d_in, const int* in_sizes, int n_in,
                              void* d_out, int out_size, void* d_ws, size_t ws_size,
                              hipStream_t stream) {
    const float* x       = (const float*)d_in[0];
    const float* grid    = (const float*)d_in[1];
    const float* c_basis = (const float*)d_in[2];
    const float* c_res   = (const float*)d_in[3];
    const float* c_spl   = (const float*)d_in[4];
    float* out = (float*)d_out;

    const size_t pw_bytes = (size_t)N_OUT * N_IN * FJ * sizeof(float);  // 768 KB
    dim3 g(BATCH / B_TILE, N_OUT / O_TILE);   // 128 x 8 = 1024 blocks

    if (ws_size >= pw_bytes) {
        float* pw = (float*)d_ws;
        pw_build<<<N_OUT * N_IN / 256, 256, 0, stream>>>(c_basis, c_res, c_spl, pw);
        kan_main<1><<<g, 256, 0, stream>>>(x, grid, c_basis, c_res, c_spl, pw, out);
    } else {
        kan_main<0><<<g, 256, 0, stream>>>(x, grid, c_basis, c_res, c_spl, nullptr, out);
    }
}

// Round 3
// 14.270 us; speedup vs baseline: 5.9447x; 3.7951x over previous
//
#include <hip/hip_runtime.h>
#include <math.h>

#define N_IN   128
#define N_OUT  128
#define BATCH  512
#define FJ     12
#define KDIM   (N_IN * FJ)        // 1536
#define NB     11

typedef __attribute__((ext_vector_type(8))) short bf16x8;   // 8 bf16 = 4 VGPRs
typedef __attribute__((ext_vector_type(4))) float f32x4;

static __device__ __forceinline__ unsigned short f2bf(float f) {
    union { float f; unsigned u; } v; v.f = f;
    unsigned r = v.u + 0x7FFF + ((v.u >> 16) & 1);    // RNE
    return (unsigned short)(r >> 16);
}

// ---- Kernel 1: build F[512][1536] (blocks 0..255) and W[128][1536] (blocks 256..319), bf16.
// F[b][i*12+j] = basis_j(x[b,i]) for j<11, F[..][i*12+11] = silu(x[b,i])
// W[o][i*12+j] = c_spl[o,i]*c_basis[o*128+i][j] for j<11, j=11 -> c_res[o,i]
__global__ __launch_bounds__(256) void prep(
    const float* __restrict__ x, const float* __restrict__ grid,
    const float* __restrict__ c_basis, const float* __restrict__ c_res,
    const float* __restrict__ c_spl,
    unsigned short* __restrict__ F, unsigned short* __restrict__ W)
{
    const int bx = blockIdx.x;
    const int t  = threadIdx.x;
    float vals[12];
    unsigned short* dst;

    if (bx < 256) {
        const int p  = bx * 256 + t;           // b*128 + i
        const float lo = grid[3];
        const float hr = 1.0f / (grid[4] - grid[3]);
        const float xv = x[p];
        const float s  = (xv - lo) * hr;       // in [0,8)
        int c = (int)s; c = c < 0 ? 0 : (c > 7 ? 7 : c);
        const float u  = s - (float)c;
        const float um = 1.0f - u;
        const float u2 = u * u, u3 = u2 * u;
        const float B0 = um * um * um * (1.0f / 6.0f);
        const float B1 = (3.0f * u3 - 6.0f * u2 + 4.0f) * (1.0f / 6.0f);
        const float B2 = (-3.0f * u3 + 3.0f * u2 + 3.0f * u + 1.0f) * (1.0f / 6.0f);
        const float B3 = u3 * (1.0f / 6.0f);
        #pragma unroll
        for (int j = 0; j < NB; ++j) {
            const int r = j - c;
            vals[j] = (r == 0) ? B0 : (r == 1) ? B1 : (r == 2) ? B2 : (r == 3) ? B3 : 0.0f;
        }
        vals[11] = xv / (1.0f + __expf(-xv));  // silu
        dst = F + (size_t)p * FJ;
    } else {
        const int e = (bx - 256) * 256 + t;    // o*128 + i
        const float s = c_spl[e];
        #pragma unroll
        for (int j = 0; j < NB; ++j) vals[j] = s * c_basis[e * NB + j];
        vals[11] = c_res[e];
        dst = W + (size_t)e * FJ;
    }

    unsigned int w[6];
    #pragma unroll
    for (int j = 0; j < 6; ++j)
        w[j] = (unsigned)f2bf(vals[2 * j]) | ((unsigned)f2bf(vals[2 * j + 1]) << 16);
    unsigned int* d32 = (unsigned int*)dst;    // 24B rows, 8B-aligned
    #pragma unroll
    for (int j = 0; j < 6; ++j) d32[j] = w[j];
}

// ---- Kernel 2: out[512][128] = F · W^T via MFMA. 256 blocks, each one 16x16 tile;
// 4 waves split K=1536 into 4x384; LDS cross-wave reduce.
__global__ __launch_bounds__(256) void gemm(
    const unsigned short* __restrict__ F, const unsigned short* __restrict__ W,
    float* __restrict__ out)
{
    __shared__ float part[4][256];
    const int t    = threadIdx.x;
    const int w    = t >> 6;                   // wave id -> K split
    const int lane = t & 63;
    const int m0   = blockIdx.x * 16;          // 32 m-blocks
    const int n0   = blockIdx.y * 16;          // 8 n-blocks
    const int row  = lane & 15;
    const int kq   = (lane >> 4) * 8;          // per-lane k offset within a 32-chunk
    const int k0   = w * (KDIM / 4);           // 384 per wave

    const bf16x8* ap = (const bf16x8*)(F + (size_t)(m0 + row) * KDIM + k0 + kq);
    const bf16x8* bp = (const bf16x8*)(W + (size_t)(n0 + row) * KDIM + k0 + kq);

    f32x4 acc = {0.f, 0.f, 0.f, 0.f};
    #pragma unroll
    for (int kk = 0; kk < (KDIM / 4) / 32; ++kk) {   // 12 steps, fully unrolled
        const bf16x8 a = ap[kk * 4];           // +32 elems per step
        const bf16x8 b = bp[kk * 4];
        acc = __builtin_amdgcn_mfma_f32_16x16x32_bf16(a, b, acc, 0, 0, 0);
    }

    // C/D layout: col = lane&15, row = (lane>>4)*4 + r   [m89-verified]
    #pragma unroll
    for (int r = 0; r < 4; ++r)
        part[w][((lane >> 4) * 4 + r) * 16 + (lane & 15)] = acc[r];
    __syncthreads();

    const float s = part[0][t] + part[1][t] + part[2][t] + part[3][t];
    out[(m0 + (t >> 4)) * N_OUT + n0 + (t & 15)] = s;
}

// =================== fallback (round-2 fp32 path) ===================
#define B_TILE 4
#define O_TILE 16
#define FSTR_FB (N_IN * 8 + 4)

__global__ __launch_bounds__(256) void kan_fb(
    const float* __restrict__ x, const float* __restrict__ grid,
    const float* __restrict__ c_basis, const float* __restrict__ c_res,
    const float* __restrict__ c_spl, float* __restrict__ out)
{
    __shared__ float f[B_TILE * FSTR_FB];
    __shared__ float part[256];
    const int t  = threadIdx.x;
    const int b0 = blockIdx.x * B_TILE;
    const int o0 = blockIdx.y * O_TILE;
    const float lo = grid[3];
    const float hr = 1.0f / (grid[4] - grid[3]);
    for (int p = t; p < B_TILE * N_IN; p += 256) {
        const int bl = p >> 7, i = p & 127;
        const float xv = x[(b0 + bl) * N_IN + i];
        const float s  = (xv - lo) * hr;
        int c = (int)s; c = c < 0 ? 0 : (c > 7 ? 7 : c);
        const float u  = s - (float)c;
        const float um = 1.0f - u;
        const float u2 = u * u, u3 = u2 * u;
        float* fp = &f[bl * FSTR_FB + i * 8];
        float4 wv = { um * um * um * (1.0f / 6.0f),
                      (3.0f * u3 - 6.0f * u2 + 4.0f) * (1.0f / 6.0f),
                      (-3.0f * u3 + 3.0f * u2 + 3.0f * u + 1.0f) * (1.0f / 6.0f),
                      u3 * (1.0f / 6.0f) };
        ((float4*)fp)[0] = wv;
        fp[4] = xv / (1.0f + __expf(-xv));
        fp[5] = (float)c;
    }
    __syncthreads();
    const int q = t >> 6, tt = t & 63, ol = tt & 15, bl = tt >> 4, og = o0 + ol;
    const float* fb = &f[bl * FSTR_FB];
    float acc = 0.0f;
    #pragma unroll 2
    for (int i = q * 32; i < q * 32 + 32; ++i) {
        const float4 wv = ((const float4*)&fb[i * 8])[0];
        const float si = fb[i * 8 + 4];
        const int   c  = (int)fb[i * 8 + 5];
        const int   e  = og * N_IN + i;
        const float* cbp = &c_basis[e * NB + c];
        const float sum = wv.x * cbp[0] + wv.y * cbp[1] + wv.z * cbp[2] + wv.w * cbp[3];
        acc += si * c_res[e] + c_spl[e] * sum;
    }
    part[t] = acc;
    __syncthreads();
    if (t < 64) {
        const int obl = t >> 4, ool = t & 15;
        out[(b0 + obl) * N_OUT + (o0 + ool)] =
            part[t] + part[t + 64] + part[t + 128] + part[t + 192];
    }
}

extern "C" void kernel_launch(void* const* d_in, const int* in_sizes, int n_in,
                              void* d_out, int out_size, void* d_ws, size_t ws_size,
                              hipStream_t stream) {
    const float* x       = (const float*)d_in[0];
    const float* grid    = (const float*)d_in[1];
    const float* c_basis = (const float*)d_in[2];
    const float* c_res   = (const float*)d_in[3];
    const float* c_spl   = (const float*)d_in[4];
    float* out = (float*)d_out;

    const size_t offF = 0;                               // 512*1536*2 = 1,572,864
    const size_t offW = (size_t)BATCH * KDIM * 2;        // 128*1536*2 =   393,216
    const size_t need = offW + (size_t)N_OUT * KDIM * 2; // 1,966,080

    if (ws_size >= need) {
        unsigned short* F = (unsigned short*)((char*)d_ws + offF);
        unsigned short* W = (unsigned short*)((char*)d_ws + offW);
        prep<<<320, 256, 0, stream>>>(x, grid, c_basis, c_res, c_spl, F, W);
        dim3 g(BATCH / 16, N_OUT / 16);                  // 32 x 8 = 256 blocks
        gemm<<<g, 256, 0, stream>>>(F, W, out);
    } else {
        dim3 g(BATCH / B_TILE, N_OUT / O_TILE);
        kan_fb<<<g, 256, 0, stream>>>(x, grid, c_basis, c_res, c_spl, out);
    }
}